// Round 1
// baseline (137.241 us; speedup 1.0000x reference)
//
#include <hip/hip_runtime.h>

#define LN_SIZE 512
#define LN_NODES 32
#define LN_BATCH 8192
#define LN_ROWS (LN_BATCH * LN_NODES)   // 262144 rows of 512 floats
#define LN_EPS 1e-5f
#define LN_SCALE 22.62741699796952f      // sqrt(512)

// ---------------------------------------------------------------------------
// Pre-kernel: one 512-thread block. Reduces w,b to the closed-form LayerNorm
// coefficients. Writes to ws:
//   ws[0..511]    = A_j   = (w_j - mean(w)) * gamma_j
//   ws[512..1023] = B_j   = (b_j - mean(b)) * gamma_j
//   ws[1024]      = c2    = SIZE * Sww      (var = c2*x^2 + c1*x + c0)
//   ws[1025]      = c1    = 2*SIZE * Swb
//   ws[1026]      = c0    = SIZE * Sbb
// ---------------------------------------------------------------------------
__global__ __launch_bounds__(LN_SIZE) void ln_pre_kernel(
    const float* __restrict__ w, const float* __restrict__ b,
    const float* __restrict__ gamma, float* __restrict__ ws) {
  __shared__ float sh[LN_SIZE];
  const int j = threadIdx.x;
  const float wj = w[j];
  const float bj = b[j];
  const float gj = gamma[j];

  auto bsum = [&](float v) -> float {
    __syncthreads();
    sh[j] = v;
    __syncthreads();
    for (int off = LN_SIZE / 2; off > 0; off >>= 1) {
      if (j < off) sh[j] += sh[j + off];
      __syncthreads();
    }
    return sh[0];
  };

  const float inv_n = 1.0f / (float)LN_SIZE;
  const float mw = bsum(wj) * inv_n;
  const float mb = bsum(bj) * inv_n;
  const float dw = wj - mw;
  const float db = bj - mb;
  const float Sww = bsum(dw * dw) * inv_n;
  const float Swb = bsum(dw * db) * inv_n;
  const float Sbb = bsum(db * db) * inv_n;

  ws[j]            = dw * gj;
  ws[LN_SIZE + j]  = db * gj;
  if (j == 0) {
    const float s2 = (float)LN_SIZE;  // SCALE^2
    ws[2 * LN_SIZE + 0] = s2 * Sww;
    ws[2 * LN_SIZE + 1] = 2.0f * s2 * Swb;
    ws[2 * LN_SIZE + 2] = s2 * Sbb;
  }
}

// ---------------------------------------------------------------------------
// Main kernel: one row (512 f32 = 2 KiB) per wave per iteration.
// Lane holds its 8 coefficients (A,B,beta) in registers; per row:
//   1 broadcast load of x, ~3 VALU, 8 FMA pairs, 2x global_store_dwordx4.
// Pure streaming-write bound.
// ---------------------------------------------------------------------------
__global__ __launch_bounds__(256) void ln_main_kernel(
    const float* __restrict__ x, const float* __restrict__ ws,
    const float* __restrict__ beta, float* __restrict__ out) {
  const int wid  = (int)((blockIdx.x * blockDim.x + threadIdx.x) >> 6);
  const int nw   = (int)((gridDim.x * blockDim.x) >> 6);
  const int lane = (int)(threadIdx.x & 63);
  const int j    = lane * 8;

  const float4 a0 = *(const float4*)(ws + j);
  const float4 a1 = *(const float4*)(ws + j + 4);
  const float4 b0 = *(const float4*)(ws + LN_SIZE + j);
  const float4 b1 = *(const float4*)(ws + LN_SIZE + j + 4);
  const float4 g0 = *(const float4*)(beta + j);
  const float4 g1 = *(const float4*)(beta + j + 4);
  const float c2 = ws[2 * LN_SIZE + 0];
  const float c1 = ws[2 * LN_SIZE + 1];
  const float c0 = ws[2 * LN_SIZE + 2];

  for (int row = wid; row < LN_ROWS; row += nw) {
    const float xv  = x[row];
    const float var = fmaf(fmaf(c2, xv, c1), xv, c0);
    const float r   = LN_SCALE * rsqrtf(var + LN_EPS);

    float4 o0, o1;
    o0.x = fmaf(fmaf(xv, a0.x, b0.x), r, g0.x);
    o0.y = fmaf(fmaf(xv, a0.y, b0.y), r, g0.y);
    o0.z = fmaf(fmaf(xv, a0.z, b0.z), r, g0.z);
    o0.w = fmaf(fmaf(xv, a0.w, b0.w), r, g0.w);
    o1.x = fmaf(fmaf(xv, a1.x, b1.x), r, g1.x);
    o1.y = fmaf(fmaf(xv, a1.y, b1.y), r, g1.y);
    o1.z = fmaf(fmaf(xv, a1.z, b1.z), r, g1.z);
    o1.w = fmaf(fmaf(xv, a1.w, b1.w), r, g1.w);

    float* dst = out + (size_t)row * LN_SIZE + j;
    *(float4*)(dst)     = o0;
    *(float4*)(dst + 4) = o1;
  }
}

extern "C" void kernel_launch(void* const* d_in, const int* in_sizes, int n_in,
                              void* d_out, int out_size, void* d_ws, size_t ws_size,
                              hipStream_t stream) {
  const float* x     = (const float*)d_in[0];
  const float* w     = (const float*)d_in[1];
  const float* b     = (const float*)d_in[2];
  const float* gamma = (const float*)d_in[3];
  const float* beta  = (const float*)d_in[4];
  float* out = (float*)d_out;
  float* ws  = (float*)d_ws;

  ln_pre_kernel<<<1, LN_SIZE, 0, stream>>>(w, b, gamma, ws);
  // 2048 blocks x 256 threads = 8192 waves; 262144 rows -> 32 rows/wave.
  ln_main_kernel<<<2048, 256, 0, stream>>>(x, ws, beta, out);
}

// Round 2
// 110.979 us; speedup vs baseline: 1.2366x; 1.2366x over previous
//
#include <hip/hip_runtime.h>

#define LN_SIZE 512
#define LN_NODES 32
#define LN_BATCH 8192
#define LN_ROWS (LN_BATCH * LN_NODES)   // 262144 rows of 512 floats
#define LN_EPS 1e-5f
#define LN_SCALE 22.62741699796952f      // sqrt(512)
#define LN_ROWS_PER_WAVE 32

// ---------------------------------------------------------------------------
// Pre-kernel: one 512-thread block. Reduces w,b to the closed-form LayerNorm
// coefficients. Writes to ws:
//   ws[0..511]    = A_j = (w_j - mean(w)) * gamma_j
//   ws[512..1023] = B_j = (b_j - mean(b)) * gamma_j
//   ws[1024..1026]= c2, c1, c0  with  var = c2*x^2 + c1*x + c0
// ---------------------------------------------------------------------------
__global__ __launch_bounds__(LN_SIZE) void ln_pre_kernel(
    const float* __restrict__ w, const float* __restrict__ b,
    const float* __restrict__ gamma, float* __restrict__ ws) {
  __shared__ float sh[LN_SIZE];
  const int j = threadIdx.x;
  const float wj = w[j];
  const float bj = b[j];
  const float gj = gamma[j];

  auto bsum = [&](float v) -> float {
    __syncthreads();
    sh[j] = v;
    __syncthreads();
    for (int off = LN_SIZE / 2; off > 0; off >>= 1) {
      if (j < off) sh[j] += sh[j + off];
      __syncthreads();
    }
    return sh[0];
  };

  const float inv_n = 1.0f / (float)LN_SIZE;
  const float mw = bsum(wj) * inv_n;
  const float mb = bsum(bj) * inv_n;
  const float dw = wj - mw;
  const float db = bj - mb;
  const float Sww = bsum(dw * dw) * inv_n;
  const float Swb = bsum(dw * db) * inv_n;
  const float Sbb = bsum(db * db) * inv_n;

  ws[j]            = dw * gj;
  ws[LN_SIZE + j]  = db * gj;
  if (j == 0) {
    const float s2 = (float)LN_SIZE;  // SCALE^2
    ws[2 * LN_SIZE + 0] = s2 * Sww;
    ws[2 * LN_SIZE + 1] = 2.0f * s2 * Swb;
    ws[2 * LN_SIZE + 2] = s2 * Sbb;
  }
}

// ---------------------------------------------------------------------------
// Main kernel: each wave owns 32 CONTIGUOUS rows (64 KiB of output).
// All 32 x-values + their rsqrt factors are computed up front (one vector
// load, one vector rsqrt); the unrolled store loop has NO global loads, so
// the store stream is never drained by vmcnt waits -> fill-kernel-like
// pure write throughput.
// ---------------------------------------------------------------------------
__global__ __launch_bounds__(256) void ln_main_kernel(
    const float* __restrict__ x, const float* __restrict__ ws,
    const float* __restrict__ beta, float* __restrict__ out) {
  const int wid  = (int)((blockIdx.x * blockDim.x + threadIdx.x) >> 6);
  const int lane = (int)(threadIdx.x & 63);
  const int j    = lane * 8;

  const float4 a0 = *(const float4*)(ws + j);
  const float4 a1 = *(const float4*)(ws + j + 4);
  const float4 b0 = *(const float4*)(ws + LN_SIZE + j);
  const float4 b1 = *(const float4*)(ws + LN_SIZE + j + 4);
  const float4 g0 = *(const float4*)(beta + j);
  const float4 g1 = *(const float4*)(beta + j + 4);
  const float c2 = ws[2 * LN_SIZE + 0];
  const float c1 = ws[2 * LN_SIZE + 1];
  const float c0 = ws[2 * LN_SIZE + 2];

  const int row0 = wid * LN_ROWS_PER_WAVE;
  if (row0 >= LN_ROWS) return;

  // Lanes 0..31 hold this wave's 32 x values (lanes 32..63 mirror them).
  const float xv  = x[row0 + (lane & 31)];
  const float var = fmaf(fmaf(c2, xv, c1), xv, c0);
  const float rv  = LN_SCALE * rsqrtf(var + LN_EPS);

  float* dst = out + (size_t)row0 * LN_SIZE + j;
#pragma unroll
  for (int i = 0; i < LN_ROWS_PER_WAVE; ++i) {
    const float xi = __shfl(xv, i);
    const float ri = __shfl(rv, i);

    float4 o0, o1;
    o0.x = fmaf(fmaf(xi, a0.x, b0.x), ri, g0.x);
    o0.y = fmaf(fmaf(xi, a0.y, b0.y), ri, g0.y);
    o0.z = fmaf(fmaf(xi, a0.z, b0.z), ri, g0.z);
    o0.w = fmaf(fmaf(xi, a0.w, b0.w), ri, g0.w);
    o1.x = fmaf(fmaf(xi, a1.x, b1.x), ri, g1.x);
    o1.y = fmaf(fmaf(xi, a1.y, b1.y), ri, g1.y);
    o1.z = fmaf(fmaf(xi, a1.z, b1.z), ri, g1.z);
    o1.w = fmaf(fmaf(xi, a1.w, b1.w), ri, g1.w);

    *(float4*)(dst)     = o0;
    *(float4*)(dst + 4) = o1;
    dst += LN_SIZE;
  }
}

extern "C" void kernel_launch(void* const* d_in, const int* in_sizes, int n_in,
                              void* d_out, int out_size, void* d_ws, size_t ws_size,
                              hipStream_t stream) {
  const float* x     = (const float*)d_in[0];
  const float* w     = (const float*)d_in[1];
  const float* b     = (const float*)d_in[2];
  const float* gamma = (const float*)d_in[3];
  const float* beta  = (const float*)d_in[4];
  float* out = (float*)d_out;
  float* ws  = (float*)d_ws;

  ln_pre_kernel<<<1, LN_SIZE, 0, stream>>>(w, b, gamma, ws);
  // 2048 blocks x 256 threads = 8192 waves; 262144 rows / 32 rows-per-wave.
  ln_main_kernel<<<2048, 256, 0, stream>>>(x, ws, beta, out);
}